// Round 4
// baseline (730.665 us; speedup 1.0000x reference)
//
#include <hip/hip_runtime.h>

// Problem dims (LRNetLinear): out = B x O, x = B x I, weights O x I
#define I_DIM 4096
#define O_DIM 4096
#define B_DIM 4096

typedef _Float16 f16;
typedef __attribute__((ext_vector_type(8))) _Float16 f16x8;
typedef __attribute__((ext_vector_type(4))) float f32x4;

struct f16pair { f16 m, v; };

// ---------------------------------------------------------------------------
// Weight transform: 3-way softmax stats -> (w_mean, w_var) in fp16
// ---------------------------------------------------------------------------
__device__ inline f16pair lr_wmv(float tn, float tp, float s) {
    float m = fmaxf(fmaxf(tn, tp), 0.0f);
    float en = __expf(tn - m);
    float ez = __expf(-m);
    float ep = __expf(tp - m);
    float inv = __builtin_amdgcn_rcpf(en + ez + ep);
    float pn = en * inv, pp = ep * inv;
    float d = pp - pn;
    f16pair r;
    r.m = (f16)(d * s);
    r.v = (f16)((pp + pn - d * d) * (s * s));
    return r;
}

// ---------------------------------------------------------------------------
// Fused prep (8 elems/thread both paths) — unchanged this round.
// ---------------------------------------------------------------------------
__global__ void prep_all(const float4* __restrict__ x, f16x8* __restrict__ xb8,
                         const float4* __restrict__ tn4, const float4* __restrict__ tp4,
                         const float4* __restrict__ sc4,
                         f16x8* __restrict__ wm8, f16x8* __restrict__ wv8,
                         int nbx) {
    const int bid = blockIdx.x;
    if (bid < nbx) {
        size_t i = (size_t)bid * blockDim.x + threadIdx.x;
        float4 a = x[2 * i];
        float4 b = x[2 * i + 1];
        f16x8 o;
        o[0] = (f16)a.x; o[1] = (f16)a.y; o[2] = (f16)a.z; o[3] = (f16)a.w;
        o[4] = (f16)b.x; o[5] = (f16)b.y; o[6] = (f16)b.z; o[7] = (f16)b.w;
        xb8[i] = o;
    } else {
        size_t i = (size_t)(bid - nbx) * blockDim.x + threadIdx.x;
        float4 a0 = tn4[2 * i], a1 = tn4[2 * i + 1];
        float4 b0 = tp4[2 * i], b1 = tp4[2 * i + 1];
        float4 s0 = sc4[2 * i], s1 = sc4[2 * i + 1];
        f16x8 om, ov;
        f16pair p;
        p = lr_wmv(a0.x, b0.x, s0.x); om[0] = p.m; ov[0] = p.v;
        p = lr_wmv(a0.y, b0.y, s0.y); om[1] = p.m; ov[1] = p.v;
        p = lr_wmv(a0.z, b0.z, s0.z); om[2] = p.m; ov[2] = p.v;
        p = lr_wmv(a0.w, b0.w, s0.w); om[3] = p.m; ov[3] = p.v;
        p = lr_wmv(a1.x, b1.x, s1.x); om[4] = p.m; ov[4] = p.v;
        p = lr_wmv(a1.y, b1.y, s1.y); om[5] = p.m; ov[5] = p.v;
        p = lr_wmv(a1.z, b1.z, s1.z); om[6] = p.m; ov[6] = p.v;
        p = lr_wmv(a1.w, b1.w, s1.w); om[7] = p.m; ov[7] = p.v;
        wm8[i] = om;
        wv8[i] = ov;
    }
}

// ---------------------------------------------------------------------------
// Fused dual GEMM, 8-phase pipeline, fragment double-buffered, with
// SCHED_GROUP_BARRIER-pinned MFMA/DS interleave (T19):
//   BM=256 x BN=128, BK=64, 512 threads = 8 waves (4M x 2N), 64x64 dual acc.
//   LDS 128 KB (2 K-tile buffers x {X 32K | Wm 16K | Wv 16K}), XOR-swizzled.
//   ROUND-4 CHANGE: round-3 PMC closed the books — phase time 1186cy =
//   MFMA-pipe 621cy + LDS-port 578cy, perfectly ADDITIVE: in-order issue
//   keeps each wave's ds_reads stuck behind its 16-MFMA cluster, so the LDS
//   port idles during MFMA and vice versa. Fix: sched_group_barrier pins an
//   emitted-order interleave {2 MFMA, 1 DS_READ} (VALU a2 groups feeding the
//   accV MFMAs, VMEM staging mid-phase), so reads issue during the early
//   MFMAs and the LDS port drains UNDER the matrix pipe. setprio removed
//   from the phase body (side-effecting intrinsic would split the scheduling
//   region and defeat the interleave; T5 is null in lockstep phases (m190)).
//   No hazard-semantics change: reads stay between the same two barriers,
//   vmcnt publication schedule identical to round-3 (audited there).
// ---------------------------------------------------------------------------
#define BM 256
#define BN 128
#define BK 64

__device__ inline void gl_lds16(const f16* g, f16* l) {
    __builtin_amdgcn_global_load_lds(
        (const __attribute__((address_space(1))) unsigned int*)g,
        (__attribute__((address_space(3))) unsigned int*)l,
        16, 0, 0);
}

#define VM8 asm volatile("s_waitcnt vmcnt(8)")
#define VM6 asm volatile("s_waitcnt vmcnt(6)")
#define VM4 asm volatile("s_waitcnt vmcnt(4)")
#define VM0 asm volatile("s_waitcnt vmcnt(0)")
#define VMNONE (void)0

// sched_group_barrier masks (LLVM SchedGroupMask): VALU=0x2 MFMA=0x8
// VMEM=0x10 DS_READ=0x100
#define SGB(m, n) __builtin_amdgcn_sched_group_barrier((m), (n), 0)

__global__ __launch_bounds__(512, 2)
void fused_dual_gemm(const f16* __restrict__ Xb,
                     const f16* __restrict__ Wm, const f16* __restrict__ Wv,
                     const float* __restrict__ eps, float* __restrict__ out) {
    __shared__ f16 smem[65536];                // 128 KB
    // elem offsets: X(p,kh) = p*32768 + kh*8192            (256 rows x 32)
    //               Wm(p,kh) = 16384 + p*32768 + kh*8192   (128 rows x 32)
    //               Wv(p,kh) = Wm + 4096

    const int tid  = threadIdx.x;
    const int lane = tid & 63;
    const int wave = tid >> 6;

    const int bm = blockIdx.y * BM;
    const int bn = blockIdx.x * BN;

    // ---- staging source (per-lane pre-swizzled granule): chunk = 16 rows x 64B.
    const int srow = lane >> 2;
    const int scol = (((lane & 3) ^ ((lane >> 3) & 3)) << 3);   // elems
    const f16* gX = Xb + (size_t)(bm + 32 * wave + srow) * I_DIM + scol;
    const f16* gM = Wm + (size_t)(bn + 16 * wave + srow) * I_DIM + scol;
    const f16* gV = Wv + (size_t)(bn + 16 * wave + srow) * I_DIM + scol;
    f16* ldsX = smem + wave * 1024;            // + p*32768 + kh*8192 (+512 chunk 1)
    f16* ldsW = smem + 16384 + wave * 512;     // + p*32768 + kh*8192 (+4096 for Wv)

    // ---- fragment geometry (16x16x32: row = lane&15, granule = lane>>4)
    const int fr  = lane & 15;
    const int sg8 = (((lane >> 4) ^ ((fr >> 1) & 3)) << 3);     // swizzled granule
    const int m0 = (wave >> 1) << 6;           // 4 M-waves: 0,64,128,192
    const int n0 = (wave & 1) << 6;            // 2 N-waves: 0,64

    f32x4 accM[4][4];
    f32x4 accV[4][4];
    const f32x4 z = {0.0f, 0.0f, 0.0f, 0.0f};
#pragma unroll
    for (int mi = 0; mi < 4; ++mi)
#pragma unroll
        for (int ni = 0; ni < 4; ++ni) { accM[mi][ni] = z; accV[mi][ni] = z; }

    // fragment double-buffers (all statically indexed)
    f16x8 A0[4], A1[4], A2c[4], Ba[4], Bb[4];

#define STAGE_X(kelem, reg) do {                                               \
        gl_lds16(gX + (kelem),              ldsX + (reg));                     \
        gl_lds16(gX + (kelem) + 16 * I_DIM, ldsX + (reg) + 512);               \
    } while (0)
#define STAGE_W(kelem, reg) do {                                               \
        gl_lds16(gM + (kelem), ldsW + (reg));                                  \
        gl_lds16(gV + (kelem), ldsW + (reg) + 4096);                           \
    } while (0)

#define RD_A(DST, RX) do {                                                     \
        DST[0] = *(const f16x8*)(smem + (RX) + (m0 +  0 + fr) * 32 + sg8);     \
        DST[1] = *(const f16x8*)(smem + (RX) + (m0 + 16 + fr) * 32 + sg8);     \
        DST[2] = *(const f16x8*)(smem + (RX) + (m0 + 32 + fr) * 32 + sg8);     \
        DST[3] = *(const f16x8*)(smem + (RX) + (m0 + 48 + fr) * 32 + sg8);     \
    } while (0)
// H=0: rows n0+{0,16}+fr (ni 0,1); H=1: rows n0+{32,48}+fr (ni 2,3); m and v
#define RD_B(DST, RW, H) do {                                                  \
        DST[0] = *(const f16x8*)(smem + (RW)        + (n0 + (H)*32 +  0 + fr) * 32 + sg8); \
        DST[1] = *(const f16x8*)(smem + (RW) + 4096 + (n0 + (H)*32 +  0 + fr) * 32 + sg8); \
        DST[2] = *(const f16x8*)(smem + (RW)        + (n0 + (H)*32 + 16 + fr) * 32 + sg8); \
        DST[3] = *(const f16x8*)(smem + (RW) + 4096 + (n0 + (H)*32 + 16 + fr) * 32 + sg8); \
    } while (0)

#define MFMA16(AC, BB, NI0, NI1) do {                                          \
        _Pragma("unroll")                                                      \
        for (int mi = 0; mi < 4; ++mi) {                                       \
            accM[mi][NI0] = __builtin_amdgcn_mfma_f32_16x16x32_f16(AC[mi],  BB[0], accM[mi][NI0], 0, 0, 0); \
            accV[mi][NI0] = __builtin_amdgcn_mfma_f32_16x16x32_f16(A2c[mi], BB[1], accV[mi][NI0], 0, 0, 0); \
            accM[mi][NI1] = __builtin_amdgcn_mfma_f32_16x16x32_f16(AC[mi],  BB[2], accM[mi][NI1], 0, 0, 0); \
            accV[mi][NI1] = __builtin_amdgcn_mfma_f32_16x16x32_f16(A2c[mi], BB[3], accV[mi][NI1], 0, 0, 0); \
        }                                                                      \
    } while (0)

// even phase: a2 VALU; MFMA(ni 0,1) on AC,Ba; read Bb (4 DS); STG (2 VMEM).
// SGB pins: {4 VALU, 2 MFMA, 1 DS} x4 (a2[mi] feeds accV[mi]), VMEM mid,
// then the remaining 8 MFMA — LDS port + staging issue under the matrix pipe.
#define PH_EVEN(AC, RWcur, STG, VM) do {                                       \
        _Pragma("unroll")                                                      \
        for (int mi = 0; mi < 4; ++mi) A2c[mi] = AC[mi] * AC[mi];              \
        MFMA16(AC, Ba, 0, 1);                                                  \
        RD_B(Bb, RWcur, 1);                                                    \
        STG;                                                                   \
        SGB(0x2, 4); SGB(0x8, 2); SGB(0x100, 1);                               \
        SGB(0x2, 4); SGB(0x8, 2); SGB(0x100, 1);                               \
        SGB(0x2, 4); SGB(0x8, 2); SGB(0x100, 1);                               \
        SGB(0x2, 4); SGB(0x8, 2); SGB(0x100, 1);                               \
        SGB(0x10, 2);                                                          \
        SGB(0x8, 8);                                                           \
        VM; __builtin_amdgcn_s_barrier();                                      \
    } while (0)
// odd phase: MFMA(ni 2,3) on AC,Bb; read ANext (4 DS) + Ba (4 DS); STG (2 VMEM).
// SGB pins: {2 MFMA, 1 DS} x4, VMEM, {2 MFMA, 1 DS} x4.
#define PH_ODD(AC, ANext, RXn, RWn, STG, VM) do {                              \
        MFMA16(AC, Bb, 2, 3);                                                  \
        RD_A(ANext, RXn);                                                      \
        RD_B(Ba, RWn, 0);                                                      \
        STG;                                                                   \
        SGB(0x8, 2); SGB(0x100, 1);                                            \
        SGB(0x8, 2); SGB(0x100, 1);                                            \
        SGB(0x8, 2); SGB(0x100, 1);                                            \
        SGB(0x8, 2); SGB(0x100, 1);                                            \
        SGB(0x10, 2);                                                          \
        SGB(0x8, 2); SGB(0x100, 1);                                            \
        SGB(0x8, 2); SGB(0x100, 1);                                            \
        SGB(0x8, 2); SGB(0x100, 1);                                            \
        SGB(0x8, 2); SGB(0x100, 1);                                            \
        VM; __builtin_amdgcn_s_barrier();                                      \
    } while (0)

    // ---- prologue: stage {X,W}(t0)k0, {X,W}(t0)k1, {X,W}(t1)k0 = 12 loads;
    // force the oldest 4 (tile0 kh0), then preload P0's fragments.
    STAGE_X(0, 0);      STAGE_W(0, 0);
    STAGE_X(32, 8192);  STAGE_W(32, 8192);
    STAGE_X(64, 32768); STAGE_W(64, 32768);
    VM8;
    __builtin_amdgcn_s_barrier();
    RD_A(A0, 0);
    RD_B(Ba, 16384, 0);

    // ---- main loop: 31 iterations x 2 K-tiles (tiles 0..61), prefetch 2 ahead.
    // Per phase, reads serve the NEXT phase; VM6 at even-phase ends publishes
    // each region exactly one barrier before its (shifted-early) read phase.
#pragma unroll 1
    for (int i = 0; i < 31; ++i) {
        const int kb = i * 128;
        PH_EVEN(A0, 16384,            STAGE_X(kb +  96, 40960), VM6);    // P0 t0k0 ni01
        PH_ODD (A0, A1, 8192, 24576,  STAGE_W(kb +  96, 40960), VMNONE); // P1 t0k0 ni23
        PH_EVEN(A1, 24576,            STAGE_X(kb + 128,     0), VM6);    // P2 t0k1 ni01
        PH_ODD (A1, A0, 32768, 49152, STAGE_W(kb + 128,     0), VMNONE); // P3 t0k1 ni23
        PH_EVEN(A0, 49152,            STAGE_X(kb + 160,  8192), VM6);    // P4 t1k0 ni01
        PH_ODD (A0, A1, 40960, 57344, STAGE_W(kb + 160,  8192), VMNONE); // P5 t1k0 ni23
        PH_EVEN(A1, 57344,            STAGE_X(kb + 192, 32768), VM6);    // P6 t1k1 ni01
        PH_ODD (A1, A0, 0, 16384,     STAGE_W(kb + 192, 32768), VMNONE); // P7 t1k1 ni23
    }

    // ---- tail: tiles 62,63. Only X/W(63,k1) still to issue; drain 6->4->0,
    // each VM placed one phase before the region's read (audited).
    PH_EVEN(A0, 16384,            STAGE_X(4064, 40960), VM6);    // TP0
    PH_ODD (A0, A1, 8192, 24576,  STAGE_W(4064, 40960), VMNONE); // TP1
    PH_EVEN(A1, 24576,            VMNONE, VM4);                  // TP2
    PH_ODD (A1, A0, 32768, 49152, VMNONE, VMNONE);               // TP3
    PH_EVEN(A0, 49152,            VMNONE, VM0);                  // TP4
    PH_ODD (A0, A1, 40960, 57344, VMNONE, VMNONE);               // TP5
    PH_EVEN(A1, 57344,            VMNONE, VMNONE);               // TP6
    MFMA16(A1, Bb, 2, 3);                                        // TP7 (no reads)

    // ---- epilogue (register-resident): C/D layout col = lane&15, row = (lane>>4)*4 + r
    const int oc  = lane & 15;
    const int orb = (lane >> 4) << 2;
#pragma unroll
    for (int mi = 0; mi < 4; ++mi) {
#pragma unroll
        for (int ni = 0; ni < 4; ++ni) {
            const int gn = bn + n0 + ni * 16 + oc;
            const int gm = bm + m0 + mi * 16 + orb;
#pragma unroll
            for (int r = 0; r < 4; ++r) {
                const size_t off = (size_t)(gm + r) * O_DIM + gn;
                const float mu = accM[mi][ni][r];
                const float vv = accV[mi][ni][r];
                out[off] = fmaf(sqrtf(fmaxf(vv, 1e-8f)), eps[off], mu);
            }
        }
    }
#undef PH_ODD
#undef PH_EVEN
#undef MFMA16
#undef RD_B
#undef RD_A
#undef STAGE_W
#undef STAGE_X
}

// ---------------------------------------------------------------------------
extern "C" void kernel_launch(void* const* d_in, const int* in_sizes, int n_in,
                              void* d_out, int out_size, void* d_ws, size_t ws_size,
                              hipStream_t stream) {
    const float* x   = (const float*)d_in[0];
    const float* tn  = (const float*)d_in[1];
    const float* tp  = (const float*)d_in[2];
    const float* sc  = (const float*)d_in[3];
    const float* eps = (const float*)d_in[4];
    float* out = (float*)d_out;

    const size_t NE = (size_t)O_DIM * I_DIM;   // 16.7M
    f16* xb = (f16*)d_ws;                      // 32 MB
    f16* wm = xb + NE;                         // 32 MB
    f16* wv = wm + NE;                         // 32 MB

    const int nbx = (int)(NE / 8 / 256);       // 8192 (x path)
    const int nbw = (int)(NE / 8 / 256);       // 8192 (weight path)
    prep_all<<<nbx + nbw, 256, 0, stream>>>(
        (const float4*)x, (f16x8*)xb,
        (const float4*)tn, (const float4*)tp, (const float4*)sc,
        (f16x8*)wm, (f16x8*)wv, nbx);

    dim3 grid(O_DIM / BN, B_DIM / BM);   // (32, 16)
    fused_dual_gemm<<<grid, 512, 0, stream>>>(
        (const f16*)xb, (const f16*)wm, (const f16*)wv, eps, out);
}

// Round 7
// 536.091 us; speedup vs baseline: 1.3629x; 1.3629x over previous
//
#include <hip/hip_runtime.h>

// Problem dims (LRNetLinear): out = B x O, x = B x I, weights O x I
#define I_DIM 4096
#define O_DIM 4096
#define B_DIM 4096

typedef _Float16 f16;
typedef __attribute__((ext_vector_type(8))) _Float16 f16x8;
typedef __attribute__((ext_vector_type(4))) float f32x4;

struct f16pair { f16 m, v; };

// ---------------------------------------------------------------------------
// Weight transform: 3-way softmax stats -> (w_mean, w_var) in fp16
// ---------------------------------------------------------------------------
__device__ inline f16pair lr_wmv(float tn, float tp, float s) {
    float m = fmaxf(fmaxf(tn, tp), 0.0f);
    float en = __expf(tn - m);
    float ez = __expf(-m);
    float ep = __expf(tp - m);
    float inv = __builtin_amdgcn_rcpf(en + ez + ep);
    float pn = en * inv, pp = ep * inv;
    float d = pp - pn;
    f16pair r;
    r.m = (f16)(d * s);
    r.v = (f16)((pp + pn - d * d) * (s * s));
    return r;
}

// ---------------------------------------------------------------------------
// Fused prep (8 elems/thread both paths) — unchanged this round.
// ---------------------------------------------------------------------------
__global__ void prep_all(const float4* __restrict__ x, f16x8* __restrict__ xb8,
                         const float4* __restrict__ tn4, const float4* __restrict__ tp4,
                         const float4* __restrict__ sc4,
                         f16x8* __restrict__ wm8, f16x8* __restrict__ wv8,
                         int nbx) {
    const int bid = blockIdx.x;
    if (bid < nbx) {
        size_t i = (size_t)bid * blockDim.x + threadIdx.x;
        float4 a = x[2 * i];
        float4 b = x[2 * i + 1];
        f16x8 o;
        o[0] = (f16)a.x; o[1] = (f16)a.y; o[2] = (f16)a.z; o[3] = (f16)a.w;
        o[4] = (f16)b.x; o[5] = (f16)b.y; o[6] = (f16)b.z; o[7] = (f16)b.w;
        xb8[i] = o;
    } else {
        size_t i = (size_t)(bid - nbx) * blockDim.x + threadIdx.x;
        float4 a0 = tn4[2 * i], a1 = tn4[2 * i + 1];
        float4 b0 = tp4[2 * i], b1 = tp4[2 * i + 1];
        float4 s0 = sc4[2 * i], s1 = sc4[2 * i + 1];
        f16x8 om, ov;
        f16pair p;
        p = lr_wmv(a0.x, b0.x, s0.x); om[0] = p.m; ov[0] = p.v;
        p = lr_wmv(a0.y, b0.y, s0.y); om[1] = p.m; ov[1] = p.v;
        p = lr_wmv(a0.z, b0.z, s0.z); om[2] = p.m; ov[2] = p.v;
        p = lr_wmv(a0.w, b0.w, s0.w); om[3] = p.m; ov[3] = p.v;
        p = lr_wmv(a1.x, b1.x, s1.x); om[4] = p.m; ov[4] = p.v;
        p = lr_wmv(a1.y, b1.y, s1.y); om[5] = p.m; ov[5] = p.v;
        p = lr_wmv(a1.z, b1.z, s1.z); om[6] = p.m; ov[6] = p.v;
        p = lr_wmv(a1.w, b1.w, s1.w); om[7] = p.m; ov[7] = p.v;
        wm8[i] = om;
        wv8[i] = ov;
    }
}

// ---------------------------------------------------------------------------
// Fused dual GEMM, 8-phase pipeline, fragment double-buffered, with
// SOURCE-ORDER MFMA/READ INTERLEAVE:
//   BM=256 x BN=128, BK=64, 512 threads = 8 waves (4M x 2N), 64x64 dual acc.
//   LDS 128 KB (2 K-tile buffers x {X 32K | Wm 16K | Wv 16K}), XOR-swizzled.
//   ROUND-7: the anti-phase branch kernel killed 4 straight container
//   attempts (rounds 5-6) — abandoned (suspect: 2x duplicated phase bodies /
//   branch lowering). Back to the verified round-3 structure (253us GEMM;
//   PMC: phase = MFMA 621cy + LDS 578cy, ADDITIVE due to in-order issue:
//   all MFMAs precede all reads in program order). This round attacks the
//   additivity WITHOUT SGB (round-4: spilled) and WITHOUT branches:
//    (a) async gl_lds staging issued FIRST in each phase (pure prefetch win;
//        audit: every staged region's last read stays >=3 barriers before
//        the stage issue — unchanged from round-3),
//    (b) each 16-MFMA cluster split into two 8-MFMA halves with the phase's
//        ds_reads placed BETWEEN the halves in source order, so the in-order
//        wave issues reads into the matrix-pipe stall gaps of the back half.
//   No live-range stretching is forced (scheduler remains free), so no
//   spill; barriers and vmcnt schedule are bit-identical to round-3.
// ---------------------------------------------------------------------------
#define BM 256
#define BN 128
#define BK 64

__device__ inline void gl_lds16(const f16* g, f16* l) {
    __builtin_amdgcn_global_load_lds(
        (const __attribute__((address_space(1))) unsigned int*)g,
        (__attribute__((address_space(3))) unsigned int*)l,
        16, 0, 0);
}

#define VM8 asm volatile("s_waitcnt vmcnt(8)")
#define VM6 asm volatile("s_waitcnt vmcnt(6)")
#define VM4 asm volatile("s_waitcnt vmcnt(4)")
#define VM0 asm volatile("s_waitcnt vmcnt(0)")
#define VMNONE (void)0

__global__ __launch_bounds__(512, 2)
void fused_dual_gemm(const f16* __restrict__ Xb,
                     const f16* __restrict__ Wm, const f16* __restrict__ Wv,
                     const float* __restrict__ eps, float* __restrict__ out) {
    __shared__ f16 smem[65536];                // 128 KB
    // elem offsets: X(p,kh) = p*32768 + kh*8192            (256 rows x 32)
    //               Wm(p,kh) = 16384 + p*32768 + kh*8192   (128 rows x 32)
    //               Wv(p,kh) = Wm + 4096

    const int tid  = threadIdx.x;
    const int lane = tid & 63;
    const int wave = tid >> 6;

    const int bm = blockIdx.y * BM;
    const int bn = blockIdx.x * BN;

    // ---- staging source (per-lane pre-swizzled granule): chunk = 16 rows x 64B.
    const int srow = lane >> 2;
    const int scol = (((lane & 3) ^ ((lane >> 3) & 3)) << 3);   // elems
    const f16* gX = Xb + (size_t)(bm + 32 * wave + srow) * I_DIM + scol;
    const f16* gM = Wm + (size_t)(bn + 16 * wave + srow) * I_DIM + scol;
    const f16* gV = Wv + (size_t)(bn + 16 * wave + srow) * I_DIM + scol;
    f16* ldsX = smem + wave * 1024;            // + p*32768 + kh*8192 (+512 chunk 1)
    f16* ldsW = smem + 16384 + wave * 512;     // + p*32768 + kh*8192 (+4096 for Wv)

    // ---- fragment geometry (16x16x32: row = lane&15, granule = lane>>4)
    const int fr  = lane & 15;
    const int sg8 = (((lane >> 4) ^ ((fr >> 1) & 3)) << 3);     // swizzled granule
    const int m0 = (wave >> 1) << 6;           // 4 M-waves: 0,64,128,192
    const int n0 = (wave & 1) << 6;            // 2 N-waves: 0,64

    f32x4 accM[4][4];
    f32x4 accV[4][4];
    const f32x4 z = {0.0f, 0.0f, 0.0f, 0.0f};
#pragma unroll
    for (int mi = 0; mi < 4; ++mi)
#pragma unroll
        for (int ni = 0; ni < 4; ++ni) { accM[mi][ni] = z; accV[mi][ni] = z; }

    // fragment double-buffers (all statically indexed)
    f16x8 A0[4], A1[4], A2c[4], Ba[4], Bb[4];

#define STAGE_X(kelem, reg) do {                                               \
        gl_lds16(gX + (kelem),              ldsX + (reg));                     \
        gl_lds16(gX + (kelem) + 16 * I_DIM, ldsX + (reg) + 512);               \
    } while (0)
#define STAGE_W(kelem, reg) do {                                               \
        gl_lds16(gM + (kelem), ldsW + (reg));                                  \
        gl_lds16(gV + (kelem), ldsW + (reg) + 4096);                           \
    } while (0)

#define RD_A(DST, RX) do {                                                     \
        DST[0] = *(const f16x8*)(smem + (RX) + (m0 +  0 + fr) * 32 + sg8);     \
        DST[1] = *(const f16x8*)(smem + (RX) + (m0 + 16 + fr) * 32 + sg8);     \
        DST[2] = *(const f16x8*)(smem + (RX) + (m0 + 32 + fr) * 32 + sg8);     \
        DST[3] = *(const f16x8*)(smem + (RX) + (m0 + 48 + fr) * 32 + sg8);     \
    } while (0)
// H=0: rows n0+{0,16}+fr (ni 0,1); H=1: rows n0+{32,48}+fr (ni 2,3); m and v
#define RD_B(DST, RW, H) do {                                                  \
        DST[0] = *(const f16x8*)(smem + (RW)        + (n0 + (H)*32 +  0 + fr) * 32 + sg8); \
        DST[1] = *(const f16x8*)(smem + (RW) + 4096 + (n0 + (H)*32 +  0 + fr) * 32 + sg8); \
        DST[2] = *(const f16x8*)(smem + (RW)        + (n0 + (H)*32 + 16 + fr) * 32 + sg8); \
        DST[3] = *(const f16x8*)(smem + (RW) + 4096 + (n0 + (H)*32 + 16 + fr) * 32 + sg8); \
    } while (0)

// 8 MFMAs: rows MI0,MI1 of the dual accumulator, columns NI0,NI1
#define MFMA8(AC, BB, NI0, NI1, MI0, MI1) do {                                 \
        accM[MI0][NI0] = __builtin_amdgcn_mfma_f32_16x16x32_f16(AC[MI0],  BB[0], accM[MI0][NI0], 0, 0, 0); \
        accV[MI0][NI0] = __builtin_amdgcn_mfma_f32_16x16x32_f16(A2c[MI0], BB[1], accV[MI0][NI0], 0, 0, 0); \
        accM[MI0][NI1] = __builtin_amdgcn_mfma_f32_16x16x32_f16(AC[MI0],  BB[2], accM[MI0][NI1], 0, 0, 0); \
        accV[MI0][NI1] = __builtin_amdgcn_mfma_f32_16x16x32_f16(A2c[MI0], BB[3], accV[MI0][NI1], 0, 0, 0); \
        accM[MI1][NI0] = __builtin_amdgcn_mfma_f32_16x16x32_f16(AC[MI1],  BB[0], accM[MI1][NI0], 0, 0, 0); \
        accV[MI1][NI0] = __builtin_amdgcn_mfma_f32_16x16x32_f16(A2c[MI1], BB[1], accV[MI1][NI0], 0, 0, 0); \
        accM[MI1][NI1] = __builtin_amdgcn_mfma_f32_16x16x32_f16(AC[MI1],  BB[2], accM[MI1][NI1], 0, 0, 0); \
        accV[MI1][NI1] = __builtin_amdgcn_mfma_f32_16x16x32_f16(A2c[MI1], BB[3], accV[MI1][NI1], 0, 0, 0); \
    } while (0)

#define A2C(AC) do {                                                           \
        _Pragma("unroll")                                                      \
        for (int mi = 0; mi < 4; ++mi) A2c[mi] = AC[mi] * AC[mi];              \
    } while (0)

// even phase: STG first (async prefetch); MFMA(ni 0,1) on AC,Ba split in two
// 8-MFMA halves with the 4 Bb ds_reads between them.
#define PH_EVEN(AC, RWcur, STG, VM) do {                                       \
        STG;                                                                   \
        A2C(AC);                                                               \
        __builtin_amdgcn_s_setprio(1);                                         \
        MFMA8(AC, Ba, 0, 1, 0, 1);                                             \
        RD_B(Bb, RWcur, 1);                                                    \
        MFMA8(AC, Ba, 0, 1, 2, 3);                                             \
        __builtin_amdgcn_s_setprio(0);                                         \
        VM; __builtin_amdgcn_s_barrier();                                      \
    } while (0)
// odd phase: STG first; MFMA(ni 2,3) on AC,Bb split with RD_A between the
// halves and RD_B after (8 reads total, 4 hidden mid-cluster).
#define PH_ODD(AC, ANext, RXn, RWn, STG, VM) do {                              \
        STG;                                                                   \
        __builtin_amdgcn_s_setprio(1);                                         \
        MFMA8(AC, Bb, 2, 3, 0, 1);                                             \
        RD_A(ANext, RXn);                                                      \
        MFMA8(AC, Bb, 2, 3, 2, 3);                                             \
        __builtin_amdgcn_s_setprio(0);                                         \
        RD_B(Ba, RWn, 0);                                                      \
        VM; __builtin_amdgcn_s_barrier();                                      \
    } while (0)

    // ---- prologue: stage {X,W}(t0)k0, {X,W}(t0)k1, {X,W}(t1)k0 = 12 loads;
    // force the oldest 4 (tile0 kh0), then preload P0's fragments.
    STAGE_X(0, 0);      STAGE_W(0, 0);
    STAGE_X(32, 8192);  STAGE_W(32, 8192);
    STAGE_X(64, 32768); STAGE_W(64, 32768);
    VM8;
    __builtin_amdgcn_s_barrier();
    RD_A(A0, 0);
    RD_B(Ba, 16384, 0);

    // ---- main loop: 31 iterations x 2 K-tiles (tiles 0..61), prefetch 2 ahead.
    // Per phase, reads serve the NEXT phase; VM6 at even-phase ends publishes
    // each region exactly one barrier before its (shifted-early) read phase.
#pragma unroll 1
    for (int i = 0; i < 31; ++i) {
        const int kb = i * 128;
        PH_EVEN(A0, 16384,            STAGE_X(kb +  96, 40960), VM6);    // P0 t0k0 ni01
        PH_ODD (A0, A1, 8192, 24576,  STAGE_W(kb +  96, 40960), VMNONE); // P1 t0k0 ni23
        PH_EVEN(A1, 24576,            STAGE_X(kb + 128,     0), VM6);    // P2 t0k1 ni01
        PH_ODD (A1, A0, 32768, 49152, STAGE_W(kb + 128,     0), VMNONE); // P3 t0k1 ni23
        PH_EVEN(A0, 49152,            STAGE_X(kb + 160,  8192), VM6);    // P4 t1k0 ni01
        PH_ODD (A0, A1, 40960, 57344, STAGE_W(kb + 160,  8192), VMNONE); // P5 t1k0 ni23
        PH_EVEN(A1, 57344,            STAGE_X(kb + 192, 32768), VM6);    // P6 t1k1 ni01
        PH_ODD (A1, A0, 0, 16384,     STAGE_W(kb + 192, 32768), VMNONE); // P7 t1k1 ni23
    }

    // ---- tail: tiles 62,63. Only X/W(63,k1) still to issue; drain 6->4->0,
    // each VM placed one phase before the region's read (audited).
    PH_EVEN(A0, 16384,            STAGE_X(4064, 40960), VM6);    // TP0
    PH_ODD (A0, A1, 8192, 24576,  STAGE_W(4064, 40960), VMNONE); // TP1
    PH_EVEN(A1, 24576,            VMNONE, VM4);                  // TP2
    PH_ODD (A1, A0, 32768, 49152, VMNONE, VMNONE);               // TP3
    PH_EVEN(A0, 49152,            VMNONE, VM0);                  // TP4
    PH_ODD (A0, A1, 40960, 57344, VMNONE, VMNONE);               // TP5
    PH_EVEN(A1, 57344,            VMNONE, VMNONE);               // TP6
    MFMA8(A1, Bb, 2, 3, 0, 1);                                   // TP7 (no reads)
    MFMA8(A1, Bb, 2, 3, 2, 3);

    // ---- epilogue (register-resident): C/D layout col = lane&15, row = (lane>>4)*4 + r
    const int oc  = lane & 15;
    const int orb = (lane >> 4) << 2;
#pragma unroll
    for (int mi = 0; mi < 4; ++mi) {
#pragma unroll
        for (int ni = 0; ni < 4; ++ni) {
            const int gn = bn + n0 + ni * 16 + oc;
            const int gm = bm + m0 + mi * 16 + orb;
#pragma unroll
            for (int r = 0; r < 4; ++r) {
                const size_t off = (size_t)(gm + r) * O_DIM + gn;
                const float mu = accM[mi][ni][r];
                const float vv = accV[mi][ni][r];
                out[off] = fmaf(sqrtf(fmaxf(vv, 1e-8f)), eps[off], mu);
            }
        }
    }
#undef PH_ODD
#undef PH_EVEN
#undef A2C
#undef MFMA8
#undef RD_B
#undef RD_A
#undef STAGE_W
#undef STAGE_X
}

// ---------------------------------------------------------------------------
extern "C" void kernel_launch(void* const* d_in, const int* in_sizes, int n_in,
                              void* d_out, int out_size, void* d_ws, size_t ws_size,
                              hipStream_t stream) {
    const float* x   = (const float*)d_in[0];
    const float* tn  = (const float*)d_in[1];
    const float* tp  = (const float*)d_in[2];
    const float* sc  = (const float*)d_in[3];
    const float* eps = (const float*)d_in[4];
    float* out = (float*)d_out;

    const size_t NE = (size_t)O_DIM * I_DIM;   // 16.7M
    f16* xb = (f16*)d_ws;                      // 32 MB
    f16* wm = xb + NE;                         // 32 MB
    f16* wv = wm + NE;                         // 32 MB

    const int nbx = (int)(NE / 8 / 256);       // 8192 (x path)
    const int nbw = (int)(NE / 8 / 256);       // 8192 (weight path)
    prep_all<<<nbx + nbw, 256, 0, stream>>>(
        (const float4*)x, (f16x8*)xb,
        (const float4*)tn, (const float4*)tp, (const float4*)sc,
        (f16x8*)wm, (f16x8*)wv, nbx);

    dim3 grid(O_DIM / BN, B_DIM / BM);   // (32, 16)
    fused_dual_gemm<<<grid, 512, 0, stream>>>(
        (const f16*)xb, (const f16*)wm, (const f16*)wv, eps, out);
}